// Round 1
// baseline (337.915 us; speedup 1.0000x reference)
//
#include <hip/hip_runtime.h>

#define LOG2E 1.44269504088896340736f

__device__ __forceinline__ float bf2f(unsigned short u) {
  union { unsigned int i; float f; } v; v.i = ((unsigned int)u) << 16; return v.f;
}
__device__ __forceinline__ unsigned short f2bf(float f) {
  union { float f; unsigned int u; } v; v.f = f;
  unsigned int r = v.u + 0x7FFFu + ((v.u >> 16) & 1u);
  return (unsigned short)(r >> 16);
}
__device__ __forceinline__ float silu_(float x) { return x / (1.0f + __expf(-x)); }
__device__ __forceinline__ unsigned int mul2bf(unsigned int a, unsigned int b) {
  float lo = bf2f((unsigned short)(a & 0xffffu)) * bf2f((unsigned short)(b & 0xffffu));
  float hi = bf2f((unsigned short)(a >> 16)) * bf2f((unsigned short)(b >> 16));
  return ((unsigned int)f2bf(hi) << 16) | (unsigned int)f2bf(lo);
}

constexpr int LC   = 128;  // chunk length (scan)
constexpr int TILE = 64;   // LDS staging tile inside a chunk
constexpr int TPB1 = 16;   // tokens per block, kernel 1

// ---------------- Kernel 1: hidden + in-proj + silu + x-proj + dt ----------------
__global__ __launch_bounds__(256) void k1_front(
    const float* __restrict__ x, const float* __restrict__ xres,
    const float* __restrict__ W_in, const float* __restrict__ W_x,
    const float* __restrict__ W_dt, const float* __restrict__ b_dt,
    float* __restrict__ hidden_out,
    unsigned short* __restrict__ dt_o, unsigned short* __restrict__ xi_o,
    unsigned short* __restrict__ zs_o,
    float* __restrict__ Bm_o, float* __restrict__ Cm_o)
{
  __shared__ unsigned short sWin[64 * 256];   // bf16 weights, [c][j]
  __shared__ float sWx[128 * 20];
  __shared__ float sWdt[4 * 128];
  __shared__ float sBdt[128];
  __shared__ float sHid[TPB1][65];            // +1 pad
  __shared__ unsigned short sXi[TPB1][128];
  __shared__ float sXdb[TPB1][4];

  const int tid = threadIdx.x;
  const int t0  = blockIdx.x * TPB1;

  // stage weights
  for (int i = tid; i < 64 * 256 / 4; i += 256) {
    float4 w = ((const float4*)W_in)[i];
    ushort4 p; p.x = f2bf(w.x); p.y = f2bf(w.y); p.z = f2bf(w.z); p.w = f2bf(w.w);
    ((ushort4*)sWin)[i] = p;
  }
  for (int i = tid; i < 128 * 20; i += 256) sWx[i] = W_x[i];
  for (int i = tid; i < 4 * 128; i += 256) sWdt[i] = W_dt[i];
  if (tid < 128) sBdt[tid] = b_dt[tid];

  // hidden = x + x_res (f32 exact), also to global (output 1)
  {
    float4 xv = ((const float4*)(x + (size_t)t0 * 64))[tid];
    float4 rv = ((const float4*)(xres + (size_t)t0 * 64))[tid];
    float4 h; h.x = xv.x + rv.x; h.y = xv.y + rv.y; h.z = xv.z + rv.z; h.w = xv.w + rv.w;
    ((float4*)(hidden_out + (size_t)t0 * 64))[tid] = h;
    int t = tid >> 4, c0 = (tid * 4) & 63;
    sHid[t][c0 + 0] = h.x; sHid[t][c0 + 1] = h.y; sHid[t][c0 + 2] = h.z; sHid[t][c0 + 3] = h.w;
  }
  __syncthreads();

  // xz = hidden @ W_in ; silu; split xi / zs.  16 tokens x 256 j, 4x4 register tile.
  {
    const int jg = tid & 63;   // j block of 4
    const int tg = tid >> 6;   // token block of 4
    const int j0 = jg * 4, tt0 = tg * 4;
    float acc[4][4];
#pragma unroll
    for (int i = 0; i < 4; ++i)
#pragma unroll
      for (int k = 0; k < 4; ++k) acc[i][k] = 0.f;
    for (int c = 0; c < 64; ++c) {
      ushort4 wv = *(const ushort4*)&sWin[c * 256 + j0];
      float w0 = bf2f(wv.x), w1 = bf2f(wv.y), w2 = bf2f(wv.z), w3 = bf2f(wv.w);
      float h0 = sHid[tt0 + 0][c], h1 = sHid[tt0 + 1][c], h2 = sHid[tt0 + 2][c], h3 = sHid[tt0 + 3][c];
      acc[0][0] += h0 * w0; acc[0][1] += h0 * w1; acc[0][2] += h0 * w2; acc[0][3] += h0 * w3;
      acc[1][0] += h1 * w0; acc[1][1] += h1 * w1; acc[1][2] += h1 * w2; acc[1][3] += h1 * w3;
      acc[2][0] += h2 * w0; acc[2][1] += h2 * w1; acc[2][2] += h2 * w2; acc[2][3] += h2 * w3;
      acc[3][0] += h3 * w0; acc[3][1] += h3 * w1; acc[3][2] += h3 * w2; acc[3][3] += h3 * w3;
    }
#pragma unroll
    for (int i = 0; i < 4; ++i) {
      int tt = tt0 + i; int t = t0 + tt;
      float s0v = silu_(acc[i][0]), s1v = silu_(acc[i][1]), s2v = silu_(acc[i][2]), s3v = silu_(acc[i][3]);
      ushort4 pk; pk.x = f2bf(s0v); pk.y = f2bf(s1v); pk.z = f2bf(s2v); pk.w = f2bf(s3v);
      if (j0 < 128) {
        *(ushort4*)&sXi[tt][j0] = pk;
        *(ushort4*)(xi_o + (size_t)t * 128 + j0) = pk;
      } else {
        *(ushort4*)(zs_o + (size_t)t * 128 + (j0 - 128)) = pk;
      }
    }
  }
  __syncthreads();

  // xdb = xi @ W_x -> dt_r(4) | B(8) | C(8)
  for (int idx = tid; idx < TPB1 * 20; idx += 256) {
    int tt = idx / 20, k = idx - tt * 20;
    float accv = 0.f;
    for (int i = 0; i < 128; ++i) accv += bf2f(sXi[tt][i]) * sWx[i * 20 + k];
    int t = t0 + tt;
    if (k < 4)       sXdb[tt][k] = accv;
    else if (k < 12) Bm_o[(size_t)t * 8 + (k - 4)]  = accv;
    else             Cm_o[(size_t)t * 8 + (k - 12)] = accv;
  }
  __syncthreads();

  // dt = softplus(dt_r @ W_dt + b_dt)
  for (int idx = tid; idx < TPB1 * 128; idx += 256) {
    int tt = idx >> 7, d = idx & 127;
    float v = sBdt[d];
#pragma unroll
    for (int r = 0; r < 4; ++r) v += sXdb[tt][r] * sWdt[r * 128 + d];
    float dt = (v > 20.f) ? v : log1pf(__expf(v));
    dt_o[(size_t)(t0 + tt) * 128 + d] = f2bf(dt);
  }
}

// ---------------- Kernel 2: per-chunk aggregates (A_prod, B_agg) ----------------
__global__ __launch_bounds__(256) void k2_agg(
    const unsigned short* __restrict__ dt_g, const unsigned short* __restrict__ xi_g,
    const float* __restrict__ Bm_g, const float* __restrict__ A_log,
    float* __restrict__ aggA, float* __restrict__ aggB)
{
  __shared__ unsigned short sDt[TILE * 128];
  __shared__ unsigned short sXi[TILE * 128];
  __shared__ float sBm[TILE * 8];
  const int tid = threadIdx.x;
  const int d = tid >> 1, sh = tid & 1, s0 = sh * 4;
  const int ck = blockIdx.x;

  float4 al = *(const float4*)(A_log + d * 8 + s0);
  float A2[4];
  A2[0] = -__expf(al.x) * LOG2E; A2[1] = -__expf(al.y) * LOG2E;
  A2[2] = -__expf(al.z) * LOG2E; A2[3] = -__expf(al.w) * LOG2E;
  float P[4] = {1.f, 1.f, 1.f, 1.f}, Bg[4] = {0.f, 0.f, 0.f, 0.f};

  for (int tile = 0; tile < LC / TILE; ++tile) {
    int gt0 = ck * LC + tile * TILE;
    __syncthreads();
    const uint4* srcD = (const uint4*)(dt_g + (size_t)gt0 * 128);
    const uint4* srcX = (const uint4*)(xi_g + (size_t)gt0 * 128);
    for (int i = tid; i < TILE * 128 * 2 / 16; i += 256) { ((uint4*)sDt)[i] = srcD[i]; ((uint4*)sXi)[i] = srcX[i]; }
    const uint4* srcB = (const uint4*)(Bm_g + (size_t)gt0 * 8);
    for (int i = tid; i < TILE * 8 / 4; i += 256) ((uint4*)sBm)[i] = srcB[i];
    __syncthreads();
#pragma unroll 4
    for (int t = 0; t < TILE; ++t) {
      float dtv = bf2f(sDt[t * 128 + d]);
      float dx  = dtv * bf2f(sXi[t * 128 + d]);
      float4 bm = *(const float4*)&sBm[t * 8 + s0];
      float a;
      a = exp2f(dtv * A2[0]); P[0] *= a; Bg[0] = Bg[0] * a + dx * bm.x;
      a = exp2f(dtv * A2[1]); P[1] *= a; Bg[1] = Bg[1] * a + dx * bm.y;
      a = exp2f(dtv * A2[2]); P[2] *= a; Bg[2] = Bg[2] * a + dx * bm.z;
      a = exp2f(dtv * A2[3]); P[3] *= a; Bg[3] = Bg[3] * a + dx * bm.w;
    }
  }
  float4 pv; pv.x = P[0];  pv.y = P[1];  pv.z = P[2];  pv.w = P[3];
  float4 bv; bv.x = Bg[0]; bv.y = Bg[1]; bv.z = Bg[2]; bv.w = Bg[3];
  *(float4*)(aggA + (size_t)ck * 1024 + tid * 4) = pv;
  *(float4*)(aggB + (size_t)ck * 1024 + tid * 4) = bv;
}

// ---------------- Kernel 2.5: serial scan over chunk aggregates ----------------
__global__ __launch_bounds__(256) void k25_scan(
    const float* __restrict__ aggA, const float* __restrict__ aggB,
    float* __restrict__ pref, int NC)
{
  int ds = blockIdx.x * 256 + threadIdx.x;  // 0..1023
  float h = 0.f;
#pragma unroll 8
  for (int ck = 0; ck < NC; ++ck) {
    float a = aggA[(size_t)ck * 1024 + ds];
    float b = aggB[(size_t)ck * 1024 + ds];
    pref[(size_t)ck * 1024 + ds] = h;
    h = fmaf(a, h, b);
  }
}

// ---------------- Kernel 3a: apply prefix, produce y_pre (before *silu(z)) ----------------
__global__ __launch_bounds__(256) void k3_apply(
    const unsigned short* dt_g, const unsigned short* __restrict__ xi_g,
    const float* __restrict__ Bm_g, const float* __restrict__ Cm_g,
    const float* __restrict__ A_log, const float* __restrict__ Dvec,
    const float* __restrict__ pref,
    unsigned short* y_o)   // ALIASES dt_g buffer (safe: write only after staging)
{
  __shared__ unsigned short sDt[TILE * 128];
  __shared__ unsigned short sXi[TILE * 128];
  __shared__ float sBm[TILE * 8];
  __shared__ float sCm[TILE * 8];
  const int tid = threadIdx.x;
  const int d = tid >> 1, sh = tid & 1, s0 = sh * 4;
  const int ck = blockIdx.x;

  float4 al = *(const float4*)(A_log + d * 8 + s0);
  float A2[4];
  A2[0] = -__expf(al.x) * LOG2E; A2[1] = -__expf(al.y) * LOG2E;
  A2[2] = -__expf(al.z) * LOG2E; A2[3] = -__expf(al.w) * LOG2E;
  float4 h0 = *(const float4*)(pref + (size_t)ck * 1024 + tid * 4);
  float h[4] = {h0.x, h0.y, h0.z, h0.w};
  float Dd = Dvec[d];

  for (int tile = 0; tile < LC / TILE; ++tile) {
    int gt0 = ck * LC + tile * TILE;
    __syncthreads();
    const uint4* srcD = (const uint4*)(dt_g + (size_t)gt0 * 128);
    const uint4* srcX = (const uint4*)(xi_g + (size_t)gt0 * 128);
    for (int i = tid; i < TILE * 128 * 2 / 16; i += 256) { ((uint4*)sDt)[i] = srcD[i]; ((uint4*)sXi)[i] = srcX[i]; }
    const uint4* srcB = (const uint4*)(Bm_g + (size_t)gt0 * 8);
    const uint4* srcC = (const uint4*)(Cm_g + (size_t)gt0 * 8);
    for (int i = tid; i < TILE * 8 / 4; i += 256) { ((uint4*)sBm)[i] = srcB[i]; ((uint4*)sCm)[i] = srcC[i]; }
    __syncthreads();
#pragma unroll 4
    for (int t = 0; t < TILE; ++t) {
      float dtv = bf2f(sDt[t * 128 + d]);
      float xiv = bf2f(sXi[t * 128 + d]);
      float dx  = dtv * xiv;
      float4 bm = *(const float4*)&sBm[t * 8 + s0];
      float4 cm = *(const float4*)&sCm[t * 8 + s0];
      float a, yp = 0.f;
      a = exp2f(dtv * A2[0]); h[0] = h[0] * a + dx * bm.x; yp += h[0] * cm.x;
      a = exp2f(dtv * A2[1]); h[1] = h[1] * a + dx * bm.y; yp += h[1] * cm.y;
      a = exp2f(dtv * A2[2]); h[2] = h[2] * a + dx * bm.z; yp += h[2] * cm.z;
      a = exp2f(dtv * A2[3]); h[3] = h[3] * a + dx * bm.w; yp += h[3] * cm.w;
      yp += __shfl_xor(yp, 1);
      float y = yp + Dd * xiv;
      if (sh == 0) y_o[(size_t)(gt0 + t) * 128 + d] = f2bf(y);
    }
  }
}

// ---------------- Kernel 3b: out = (y*silu(z)) @ W_out + hidden ----------------
__global__ __launch_bounds__(256) void k3b_out(
    const unsigned short* __restrict__ y_g, const unsigned short* __restrict__ zs_g,
    const float* __restrict__ W_out, const float* __restrict__ hidden_g,
    float* __restrict__ out)
{
  __shared__ unsigned int sY[64 * 65];       // [t][kk2] padded, uint = 2 bf16
  __shared__ unsigned short sWo[128 * 64];
  const int tid = threadIdx.x;
  const int tb = blockIdx.x * 64;

  for (int i = tid; i < 2048; i += 256) {
    float4 w = ((const float4*)W_out)[i];
    ushort4 p; p.x = f2bf(w.x); p.y = f2bf(w.y); p.z = f2bf(w.z); p.w = f2bf(w.w);
    ((ushort4*)sWo)[i] = p;
  }
  for (int i = tid; i < 1024; i += 256) {
    uint4 yv = ((const uint4*)(y_g + (size_t)tb * 128))[i];
    uint4 zv = ((const uint4*)(zs_g + (size_t)tb * 128))[i];
    unsigned int r0 = mul2bf(yv.x, zv.x);
    unsigned int r1 = mul2bf(yv.y, zv.y);
    unsigned int r2 = mul2bf(yv.z, zv.z);
    unsigned int r3 = mul2bf(yv.w, zv.w);
    int e = i * 4;
    sY[((e) >> 6) * 65 + ((e) & 63)]     = r0;
    sY[((e + 1) >> 6) * 65 + ((e + 1) & 63)] = r1;
    sY[((e + 2) >> 6) * 65 + ((e + 2) & 63)] = r2;
    sY[((e + 3) >> 6) * 65 + ((e + 3) & 63)] = r3;
  }
  __syncthreads();

  const int ci = tid & 15, ti = tid >> 4;
  const int c0 = ci * 4, tt0 = ti * 4;
  float acc[4][4];
#pragma unroll
  for (int i = 0; i < 4; ++i)
#pragma unroll
    for (int j = 0; j < 4; ++j) acc[i][j] = 0.f;

  for (int kk2 = 0; kk2 < 64; ++kk2) {
    ushort4 wa = *(const ushort4*)&sWo[(2 * kk2) * 64 + c0];
    ushort4 wb = *(const ushort4*)&sWo[(2 * kk2 + 1) * 64 + c0];
    float wa0 = bf2f(wa.x), wa1 = bf2f(wa.y), wa2 = bf2f(wa.z), wa3 = bf2f(wa.w);
    float wb0 = bf2f(wb.x), wb1 = bf2f(wb.y), wb2 = bf2f(wb.z), wb3 = bf2f(wb.w);
#pragma unroll
    for (int i = 0; i < 4; ++i) {
      unsigned int u = sY[(tt0 + i) * 65 + kk2];
      float ylo = bf2f((unsigned short)(u & 0xffffu));
      float yhi = bf2f((unsigned short)(u >> 16));
      acc[i][0] += ylo * wa0 + yhi * wb0;
      acc[i][1] += ylo * wa1 + yhi * wb1;
      acc[i][2] += ylo * wa2 + yhi * wb2;
      acc[i][3] += ylo * wa3 + yhi * wb3;
    }
  }
#pragma unroll
  for (int i = 0; i < 4; ++i) {
    int t = tb + tt0 + i;
    float4 hv = *(const float4*)(hidden_g + (size_t)t * 64 + c0);
    float4 o;
    o.x = acc[i][0] + hv.x; o.y = acc[i][1] + hv.y;
    o.z = acc[i][2] + hv.z; o.w = acc[i][3] + hv.w;
    *(float4*)(out + (size_t)t * 64 + c0) = o;
  }
}

extern "C" void kernel_launch(void* const* d_in, const int* in_sizes, int n_in,
                              void* d_out, int out_size, void* d_ws, size_t ws_size,
                              hipStream_t stream) {
  const float* x     = (const float*)d_in[0];
  const float* xres  = (const float*)d_in[1];
  // d_in[2] = scale_id (unused by reference)
  const float* W_in  = (const float*)d_in[3];
  const float* W_x   = (const float*)d_in[4];
  const float* W_dt  = (const float*)d_in[5];
  const float* b_dt  = (const float*)d_in[6];
  const float* A_log = (const float*)d_in[7];
  const float* Dv    = (const float*)d_in[8];
  const float* W_out = (const float*)d_in[9];

  const int T  = in_sizes[0] / 64;   // 65536
  const int NC = T / LC;             // 512

  float* out_x = (float*)d_out;                     // x_out: T*64
  float* out_h = (float*)d_out + (size_t)T * 64;    // hidden: T*64

  char* ws = (char*)d_ws;
  unsigned short* dt_b = (unsigned short*)ws; ws += (size_t)T * 128 * 2;
  unsigned short* xi_b = (unsigned short*)ws; ws += (size_t)T * 128 * 2;
  unsigned short* zs_b = (unsigned short*)ws; ws += (size_t)T * 128 * 2;
  float* Bm_b = (float*)ws; ws += (size_t)T * 8 * 4;
  float* Cm_b = (float*)ws; ws += (size_t)T * 8 * 4;
  float* aggA = (float*)ws; ws += (size_t)NC * 1024 * 4;
  float* aggB = (float*)ws; ws += (size_t)NC * 1024 * 4;
  float* pref = (float*)ws; ws += (size_t)NC * 1024 * 4;
  unsigned short* y_b = dt_b;  // alias: dt dead after k3_apply consumes each tile

  k1_front<<<T / TPB1, 256, 0, stream>>>(x, xres, W_in, W_x, W_dt, b_dt,
                                         out_h, dt_b, xi_b, zs_b, Bm_b, Cm_b);
  k2_agg<<<NC, 256, 0, stream>>>(dt_b, xi_b, Bm_b, A_log, aggA, aggB);
  k25_scan<<<4, 256, 0, stream>>>(aggA, aggB, pref, NC);
  k3_apply<<<NC, 256, 0, stream>>>(dt_b, xi_b, Bm_b, Cm_b, A_log, Dv, pref, y_b);
  k3b_out<<<T / 64, 256, 0, stream>>>(y_b, zs_b, W_out, out_h, out_x);
}

// Round 2
// 248.227 us; speedup vs baseline: 1.3613x; 1.3613x over previous
//
#include <hip/hip_runtime.h>

#define LOG2E 1.44269504088896340736f
#define RLOG2E 0.69314718055994530942f

using short8 = __attribute__((ext_vector_type(8))) short;
using f32x4  = __attribute__((ext_vector_type(4))) float;

__device__ __forceinline__ float bf2f(unsigned short u) {
  union { unsigned int i; float f; } v; v.i = ((unsigned int)u) << 16; return v.f;
}
__device__ __forceinline__ unsigned short f2bf(float f) {
  union { float f; unsigned int u; } v; v.f = f;
  unsigned int r = v.u + 0x7FFFu + ((v.u >> 16) & 1u);
  return (unsigned short)(r >> 16);
}
__device__ __forceinline__ float silu_(float x) {
  return x * __builtin_amdgcn_rcpf(1.0f + __expf(-x));
}
__device__ __forceinline__ unsigned int mul2bf(unsigned int a, unsigned int b) {
  float lo = bf2f((unsigned short)(a & 0xffffu)) * bf2f((unsigned short)(b & 0xffffu));
  float hi = bf2f((unsigned short)(a >> 16)) * bf2f((unsigned short)(b >> 16));
  return ((unsigned int)f2bf(hi) << 16) | (unsigned int)f2bf(lo);
}
__device__ __forceinline__ f32x4 mfma16(short8 a, short8 b, f32x4 c) {
  return __builtin_amdgcn_mfma_f32_16x16x32_bf16(a, b, c, 0, 0, 0);
}

constexpr int LC = 64;   // chunk length == tokens per block

// ---------------- k0: one-time weight conversion / transpose to bf16 ----------------
// WinT [256 n][64 k], WxT [32 n][128 k] (pad n>=20 with 0), WoT [64 n][128 k]
__global__ __launch_bounds__(256) void k0_prep(
    const float* __restrict__ W_in, const float* __restrict__ W_x,
    const float* __restrict__ W_out,
    unsigned short* __restrict__ WinT, unsigned short* __restrict__ WxT,
    unsigned short* __restrict__ WoT)
{
  int flat = blockIdx.x * 256 + threadIdx.x;
  if (flat < 16384) {
    int n = flat >> 6, k = flat & 63;
    WinT[flat] = f2bf(W_in[k * 256 + n]);
  } else if (flat < 20480) {
    int f = flat - 16384; int n = f >> 7, k = f & 127;
    WxT[f] = (n < 20) ? f2bf(W_x[k * 20 + n]) : (unsigned short)0;
  } else if (flat < 28672) {
    int f = flat - 20480; int n = f >> 7, k = f & 127;
    WoT[f] = f2bf(W_out[k * 64 + n]);
  }
}

// ---------------- k1: hidden + MFMA in-proj + silu + MFMA x-proj + dt + chunk aggregate ----------------
__global__ __launch_bounds__(256) void k1_front(
    const float* __restrict__ x, const float* __restrict__ xres,
    const unsigned short* __restrict__ gWinT, const unsigned short* __restrict__ gWxT,
    const float* __restrict__ W_dt, const float* __restrict__ b_dt,
    const float* __restrict__ A_log,
    float* __restrict__ hidden_out,
    unsigned short* __restrict__ dt_o, unsigned short* __restrict__ xi_o,
    unsigned short* __restrict__ zs_o,
    float* __restrict__ Bm_o, float* __restrict__ Cm_o,
    float* __restrict__ aggA, float* __restrict__ aggB)
{
  __shared__ __align__(16) char smem[63488];
  unsigned short* sWinT = (unsigned short*)smem;            // 32KB [256][64] swz
  unsigned short* sXZ   = (unsigned short*)smem;            // alias after MFMA1: [64][256] swz
  unsigned short* sA    = (unsigned short*)(smem + 32768);  // 8KB [64][64] swz
  unsigned short* sWxT  = (unsigned short*)(smem + 32768);  // alias: [32][128] swz
  unsigned short* sDt   = (unsigned short*)(smem + 40960);  // 16KB [64][128]
  float* sDtr = (float*)(smem + 57344);                     // [64][5]
  float* sBm  = (float*)(smem + 58624);                     // [64][9]
  float* sWdt = (float*)(smem + 60928);                     // [4][128]
  float* sBdt = (float*)(smem + 62976);                     // [128]

  const int tid  = threadIdx.x;
  const int lane = tid & 63;
  const int w    = tid >> 6;
  const int t0   = blockIdx.x * LC;
  const int ck   = blockIdx.x;

  // ---- stage WinT (swizzled), W_dt, b_dt; compute hidden -> global + sA(bf16, swz)
#pragma unroll
  for (int i = 0; i < 8; ++i) {
    int f = tid + i * 256;             // uint4 index over 256x64 bf16
    int n = f >> 3, k0 = (f & 7) * 8;
    uint4 v = ((const uint4*)gWinT)[f];
    *(uint4*)&sWinT[n * 64 + (k0 ^ ((n & 7) << 3))] = v;
  }
  for (int i = tid; i < 512; i += 256) sWdt[i] = W_dt[i];
  if (tid < 128) sBdt[tid] = b_dt[tid];
#pragma unroll
  for (int i = 0; i < 4; ++i) {
    int f = tid + i * 256;             // float4 index over 64x64 f32
    int t = f >> 4, c0 = (f & 15) * 4;
    float4 xv = ((const float4*)(x    + (size_t)t0 * 64))[f];
    float4 rv = ((const float4*)(xres + (size_t)t0 * 64))[f];
    float4 h; h.x = xv.x + rv.x; h.y = xv.y + rv.y; h.z = xv.z + rv.z; h.w = xv.w + rv.w;
    ((float4*)(hidden_out + (size_t)t0 * 64))[f] = h;
    ushort4 p; p.x = f2bf(h.x); p.y = f2bf(h.y); p.z = f2bf(h.z); p.w = f2bf(h.w);
    *(ushort4*)&sA[t * 64 + (c0 ^ ((t & 7) << 3))] = p;
  }
  __syncthreads();

  // ---- MFMA1: xz[64 tok][256 n] = hidden @ W_in ; wave w owns n in [w*64, w*64+64)
  f32x4 acc[4][4];
#pragma unroll
  for (int m = 0; m < 4; ++m)
#pragma unroll
    for (int n = 0; n < 4; ++n) acc[m][n] = (f32x4){0.f, 0.f, 0.f, 0.f};
#pragma unroll
  for (int ks = 0; ks < 2; ++ks) {
    int k0 = ks * 32 + ((lane >> 4) << 3);
    short8 af[4], bfr[4];
#pragma unroll
    for (int m = 0; m < 4; ++m) {
      int row = m * 16 + (lane & 15);
      af[m] = *(const short8*)&sA[row * 64 + (k0 ^ ((row & 7) << 3))];
    }
#pragma unroll
    for (int n = 0; n < 4; ++n) {
      int col = w * 64 + n * 16 + (lane & 15);
      bfr[n] = *(const short8*)&sWinT[col * 64 + (k0 ^ ((col & 7) << 3))];
    }
#pragma unroll
    for (int m = 0; m < 4; ++m)
#pragma unroll
      for (int n = 0; n < 4; ++n) acc[m][n] = mfma16(af[m], bfr[n], acc[m][n]);
  }
  __syncthreads();   // sWinT/sA dead

  // ---- stage WxT into sA's space (swizzled)
#pragma unroll
  for (int i = 0; i < 2; ++i) {
    int f = tid + i * 256;             // uint4 over 32x128 bf16
    int n = f >> 4, k0 = (f & 15) * 8;
    uint4 v = ((const uint4*)gWxT)[f];
    *(uint4*)&sWxT[n * 128 + (k0 ^ ((n & 7) << 3))] = v;
  }
  // ---- silu(xz) -> sXZ [64][256] swizzled (xi cols 0..127, silu(z) cols 128..255)
#pragma unroll
  for (int m = 0; m < 4; ++m)
#pragma unroll
    for (int n = 0; n < 4; ++n) {
      int col = w * 64 + n * 16 + (lane & 15);
#pragma unroll
      for (int r = 0; r < 4; ++r) {
        int tok = m * 16 + ((lane >> 4) << 2) + r;
        sXZ[tok * 256 + (col ^ ((tok & 7) << 3))] = f2bf(silu_(acc[m][n][r]));
      }
    }
  __syncthreads();

  // ---- copy xi / zs to global (coalesced uint4)
#pragma unroll
  for (int i = 0; i < 8; ++i) {
    int f = tid + i * 256;             // uint4 over 64x256 bf16
    int t = f >> 5, k0 = (f & 31) * 8;
    uint4 v = *(const uint4*)&sXZ[t * 256 + (k0 ^ ((t & 7) << 3))];
    if (k0 < 128) *(uint4*)(xi_o + (size_t)(t0 + t) * 128 + k0) = v;
    else          *(uint4*)(zs_o + (size_t)(t0 + t) * 128 + (k0 - 128)) = v;
  }

  // ---- MFMA2: xdb[64 tok][20] = xi @ W_x ; wave w owns token frag w*16..w*16+15
  f32x4 acc2[2];
  acc2[0] = (f32x4){0.f, 0.f, 0.f, 0.f};
  acc2[1] = (f32x4){0.f, 0.f, 0.f, 0.f};
#pragma unroll
  for (int ks = 0; ks < 4; ++ks) {
    int k0 = ks * 32 + ((lane >> 4) << 3);
    int arow = w * 16 + (lane & 15);
    short8 a2 = *(const short8*)&sXZ[arow * 256 + (k0 ^ ((arow & 7) << 3))];
#pragma unroll
    for (int nf = 0; nf < 2; ++nf) {
      int col = nf * 16 + (lane & 15);
      short8 b2 = *(const short8*)&sWxT[col * 128 + (k0 ^ ((col & 7) << 3))];
      acc2[nf] = mfma16(a2, b2, acc2[nf]);
    }
  }
#pragma unroll
  for (int nf = 0; nf < 2; ++nf) {
    int col = nf * 16 + (lane & 15);
#pragma unroll
    for (int r = 0; r < 4; ++r) {
      int tok = w * 16 + ((lane >> 4) << 2) + r;
      float v = acc2[nf][r];
      if (col < 4) {
        sDtr[tok * 5 + col] = v;
      } else if (col < 12) {
        sBm[tok * 9 + (col - 4)] = v;
        Bm_o[(size_t)(t0 + tok) * 8 + (col - 4)] = v;
      } else if (col < 20) {
        Cm_o[(size_t)(t0 + tok) * 8 + (col - 12)] = v;
      }
    }
  }
  __syncthreads();

  // ---- dt = softplus(dt_r @ W_dt + b_dt) -> global bf16 + sDt
#pragma unroll
  for (int i = 0; i < 16; ++i) {
    int f = tid + i * 256;             // pair index over 64x64
    int t = f >> 6, d0 = (f & 63) * 2;
    float r0 = sDtr[t * 5 + 0], r1 = sDtr[t * 5 + 1], r2 = sDtr[t * 5 + 2], r3 = sDtr[t * 5 + 3];
    unsigned int pk = 0;
#pragma unroll
    for (int q = 0; q < 2; ++q) {
      int d = d0 + q;
      float v = sBdt[d] + r0 * sWdt[d] + r1 * sWdt[128 + d] + r2 * sWdt[256 + d] + r3 * sWdt[384 + d];
      float sp = (v > 15.f) ? v : RLOG2E * __log2f(1.f + exp2f(v * LOG2E));
      pk |= ((unsigned int)f2bf(sp)) << (16 * q);
    }
    ((unsigned int*)sDt)[t * 64 + (d0 >> 1)] = pk;
    ((unsigned int*)dt_o)[(size_t)(t0 + t) * 64 + (d0 >> 1)] = pk;
  }
  __syncthreads();

  // ---- fused chunk aggregate: thread = (d = tid>>1, states s0..s0+3)
  {
    const int d = tid >> 1, sh = tid & 1, s0 = sh * 4;
    float4 al = *(const float4*)(A_log + d * 8 + s0);
    float A2[4];
    A2[0] = -__expf(al.x) * LOG2E; A2[1] = -__expf(al.y) * LOG2E;
    A2[2] = -__expf(al.z) * LOG2E; A2[3] = -__expf(al.w) * LOG2E;
    float P[4] = {1.f, 1.f, 1.f, 1.f}, Bg[4] = {0.f, 0.f, 0.f, 0.f};
#pragma unroll 4
    for (int t = 0; t < LC; ++t) {
      float dtv = bf2f(sDt[t * 128 + d]);
      float xiv = bf2f(sXZ[t * 256 + (d ^ ((t & 7) << 3))]);
      float dx  = dtv * xiv;
      float b0 = sBm[t * 9 + s0], b1 = sBm[t * 9 + s0 + 1], b2 = sBm[t * 9 + s0 + 2], b3 = sBm[t * 9 + s0 + 3];
      float a;
      a = exp2f(dtv * A2[0]); P[0] *= a; Bg[0] = fmaf(Bg[0], a, dx * b0);
      a = exp2f(dtv * A2[1]); P[1] *= a; Bg[1] = fmaf(Bg[1], a, dx * b1);
      a = exp2f(dtv * A2[2]); P[2] *= a; Bg[2] = fmaf(Bg[2], a, dx * b2);
      a = exp2f(dtv * A2[3]); P[3] *= a; Bg[3] = fmaf(Bg[3], a, dx * b3);
    }
    float4 pv; pv.x = P[0];  pv.y = P[1];  pv.z = P[2];  pv.w = P[3];
    float4 bv; bv.x = Bg[0]; bv.y = Bg[1]; bv.z = Bg[2]; bv.w = Bg[3];
    *(float4*)(aggA + (size_t)ck * 1024 + tid * 4) = pv;
    *(float4*)(aggB + (size_t)ck * 1024 + tid * 4) = bv;
  }
}

// ---------------- k25: serial scan over chunk aggregates (pref written in-place to aggA) ----------------
__global__ __launch_bounds__(256) void k25_scan(
    float* __restrict__ aggA, const float* __restrict__ aggB, int NC)
{
  int ds = blockIdx.x * 256 + threadIdx.x;  // 0..1023
  float h = 0.f;
#pragma unroll 8
  for (int ck = 0; ck < NC; ++ck) {
    float a = aggA[(size_t)ck * 1024 + ds];
    float b = aggB[(size_t)ck * 1024 + ds];
    aggA[(size_t)ck * 1024 + ds] = h;
    h = fmaf(a, h, b);
  }
}

// ---------------- k3: apply prefix, produce y (before *silu(z)) ----------------
__global__ __launch_bounds__(256) void k3_apply(
    const unsigned short* dt_g, const unsigned short* __restrict__ xi_g,
    const float* __restrict__ Bm_g, const float* __restrict__ Cm_g,
    const float* __restrict__ A_log, const float* __restrict__ Dvec,
    const float* __restrict__ pref,
    unsigned short* y_o)   // aliases dt_g buffer (safe: writes after staging)
{
  __shared__ __align__(16) char smem[37376];
  unsigned short* sDt = (unsigned short*)smem;            // [64][128]
  unsigned short* sXi = (unsigned short*)(smem + 16384);  // [64][128]
  float* sBm = (float*)(smem + 32768);                    // [64][9]
  float* sCm = (float*)(smem + 35072);                    // [64][9]

  const int tid = threadIdx.x;
  const int d = tid >> 1, sh = tid & 1, s0 = sh * 4;
  const int ck = blockIdx.x;
  const int gt0 = ck * LC;

#pragma unroll
  for (int i = 0; i < 8; ++i) {
    int f = tid + i * 256;   // uint4 over 64x128 bf16
    ((uint4*)sDt)[f] = ((const uint4*)(dt_g + (size_t)gt0 * 128))[f];
    ((uint4*)sXi)[f] = ((const uint4*)(xi_g + (size_t)gt0 * 128))[f];
  }
#pragma unroll
  for (int i = 0; i < 2; ++i) {
    int f = tid + i * 256;   // over 64x8 f32
    int r = f >> 3, c = f & 7;
    sBm[r * 9 + c] = Bm_g[(size_t)gt0 * 8 + f];
    sCm[r * 9 + c] = Cm_g[(size_t)gt0 * 8 + f];
  }

  float4 al = *(const float4*)(A_log + d * 8 + s0);
  float A2[4];
  A2[0] = -__expf(al.x) * LOG2E; A2[1] = -__expf(al.y) * LOG2E;
  A2[2] = -__expf(al.z) * LOG2E; A2[3] = -__expf(al.w) * LOG2E;
  float4 h0 = *(const float4*)(pref + (size_t)ck * 1024 + tid * 4);
  float h[4] = {h0.x, h0.y, h0.z, h0.w};
  float Dd = Dvec[d];
  __syncthreads();

#pragma unroll 4
  for (int t = 0; t < LC; ++t) {
    float dtv = bf2f(sDt[t * 128 + d]);
    float xiv = bf2f(sXi[t * 128 + d]);
    float dx  = dtv * xiv;
    float b0 = sBm[t * 9 + s0], b1 = sBm[t * 9 + s0 + 1], b2 = sBm[t * 9 + s0 + 2], b3 = sBm[t * 9 + s0 + 3];
    float c0 = sCm[t * 9 + s0], c1 = sCm[t * 9 + s0 + 1], c2 = sCm[t * 9 + s0 + 2], c3 = sCm[t * 9 + s0 + 3];
    float a, yp;
    a = exp2f(dtv * A2[0]); h[0] = fmaf(h[0], a, dx * b0); yp  = h[0] * c0;
    a = exp2f(dtv * A2[1]); h[1] = fmaf(h[1], a, dx * b1); yp += h[1] * c1;
    a = exp2f(dtv * A2[2]); h[2] = fmaf(h[2], a, dx * b2); yp += h[2] * c2;
    a = exp2f(dtv * A2[3]); h[3] = fmaf(h[3], a, dx * b3); yp += h[3] * c3;
    yp += __shfl_xor(yp, 1);
    if (sh == 0) y_o[(size_t)(gt0 + t) * 128 + d] = f2bf(yp + Dd * xiv);
  }
}

// ---------------- k3b: out = (y*silu(z)) @ W_out + hidden  (MFMA) ----------------
__global__ __launch_bounds__(256) void k3b_out(
    const unsigned short* __restrict__ y_g, const unsigned short* __restrict__ zs_g,
    const unsigned short* __restrict__ gWoT, const float* __restrict__ hidden_g,
    float* __restrict__ out)
{
  __shared__ __align__(16) char smem[32768];
  unsigned short* sY   = (unsigned short*)smem;            // [64][128] swz
  unsigned short* sWoT = (unsigned short*)(smem + 16384);  // [64][128] swz

  const int tid = threadIdx.x;
  const int lane = tid & 63;
  const int w = tid >> 6;
  const int tb = blockIdx.x * 64;

#pragma unroll
  for (int i = 0; i < 4; ++i) {
    int f = tid + i * 256;   // uint4 over 64x128 bf16
    int n = f >> 4, k0 = (f & 15) * 8;
    uint4 v = ((const uint4*)gWoT)[f];
    *(uint4*)&sWoT[n * 128 + (k0 ^ ((n & 7) << 3))] = v;
    uint4 yv = ((const uint4*)(y_g  + (size_t)tb * 128))[f];
    uint4 zv = ((const uint4*)(zs_g + (size_t)tb * 128))[f];
    uint4 p; p.x = mul2bf(yv.x, zv.x); p.y = mul2bf(yv.y, zv.y);
    p.z = mul2bf(yv.z, zv.z); p.w = mul2bf(yv.w, zv.w);
    *(uint4*)&sY[n * 128 + (k0 ^ ((n & 7) << 3))] = p;   // n==t here
  }
  __syncthreads();

  // wave w: token frag w*16.., all 4 n-frags, K=128
  f32x4 acc[4];
#pragma unroll
  for (int n = 0; n < 4; ++n) acc[n] = (f32x4){0.f, 0.f, 0.f, 0.f};
#pragma unroll
  for (int ks = 0; ks < 4; ++ks) {
    int k0 = ks * 32 + ((lane >> 4) << 3);
    int arow = w * 16 + (lane & 15);
    short8 a = *(const short8*)&sY[arow * 128 + (k0 ^ ((arow & 7) << 3))];
#pragma unroll
    for (int nf = 0; nf < 4; ++nf) {
      int col = nf * 16 + (lane & 15);
      short8 b = *(const short8*)&sWoT[col * 128 + (k0 ^ ((col & 7) << 3))];
      acc[nf] = mfma16(a, b, acc[nf]);
    }
  }
#pragma unroll
  for (int nf = 0; nf < 4; ++nf) {
    int col = nf * 16 + (lane & 15);
#pragma unroll
    for (int r = 0; r < 4; ++r) {
      int tok = w * 16 + ((lane >> 4) << 2) + r;
      size_t idx = (size_t)(tb + tok) * 64 + col;
      out[idx] = acc[nf][r] + hidden_g[idx];
    }
  }
}

extern "C" void kernel_launch(void* const* d_in, const int* in_sizes, int n_in,
                              void* d_out, int out_size, void* d_ws, size_t ws_size,
                              hipStream_t stream) {
  const float* x     = (const float*)d_in[0];
  const float* xres  = (const float*)d_in[1];
  const float* W_in  = (const float*)d_in[3];
  const float* W_x   = (const float*)d_in[4];
  const float* W_dt  = (const float*)d_in[5];
  const float* b_dt  = (const float*)d_in[6];
  const float* A_log = (const float*)d_in[7];
  const float* Dv    = (const float*)d_in[8];
  const float* W_out = (const float*)d_in[9];

  const int T  = in_sizes[0] / 64;   // 65536
  const int NB = T / LC;             // 1024 blocks == chunks
  const int NC = NB;

  float* out_x = (float*)d_out;
  float* out_h = (float*)d_out + (size_t)T * 64;

  char* ws = (char*)d_ws;
  unsigned short* dt_b = (unsigned short*)ws; ws += (size_t)T * 128 * 2;
  unsigned short* xi_b = (unsigned short*)ws; ws += (size_t)T * 128 * 2;
  unsigned short* zs_b = (unsigned short*)ws; ws += (size_t)T * 128 * 2;
  float* Bm_b = (float*)ws; ws += (size_t)T * 8 * 4;
  float* Cm_b = (float*)ws; ws += (size_t)T * 8 * 4;
  float* aggA = (float*)ws; ws += (size_t)NC * 1024 * 4;   // becomes prefix in-place
  float* aggB = (float*)ws; ws += (size_t)NC * 1024 * 4;
  unsigned short* WinT = (unsigned short*)ws; ws += 16384 * 2;
  unsigned short* WxT  = (unsigned short*)ws; ws += 4096 * 2;
  unsigned short* WoT  = (unsigned short*)ws; ws += 8192 * 2;
  unsigned short* y_b  = dt_b;  // alias

  k0_prep<<<112, 256, 0, stream>>>(W_in, W_x, W_out, WinT, WxT, WoT);
  k1_front<<<NB, 256, 0, stream>>>(x, xres, WinT, WxT, W_dt, b_dt, A_log,
                                   out_h, dt_b, xi_b, zs_b, Bm_b, Cm_b, aggA, aggB);
  k25_scan<<<4, 256, 0, stream>>>(aggA, aggB, NC);
  k3_apply<<<NB, 256, 0, stream>>>(dt_b, xi_b, Bm_b, Cm_b, A_log, Dv, aggA, y_b);
  k3b_out<<<NB, 256, 0, stream>>>(y_b, zs_b, WoT, out_h, out_x);
}

// Round 4
// 182.630 us; speedup vs baseline: 1.8503x; 1.3592x over previous
//
#include <hip/hip_runtime.h>

#define LOG2E 1.44269504088896340736f
#define RLOG2E 0.69314718055994530942f

using short8 = __attribute__((ext_vector_type(8))) short;
using f32x4  = __attribute__((ext_vector_type(4))) float;

__device__ __forceinline__ float bf2f(unsigned short u) {
  union { unsigned int i; float f; } v; v.i = ((unsigned int)u) << 16; return v.f;
}
__device__ __forceinline__ unsigned short f2bf(float f) {
  union { float f; unsigned int u; } v; v.f = f;
  unsigned int r = v.u + 0x7FFFu + ((v.u >> 16) & 1u);
  return (unsigned short)(r >> 16);
}
__device__ __forceinline__ float silu_(float x) {
  return x * __builtin_amdgcn_rcpf(1.0f + __expf(-x));
}
__device__ __forceinline__ unsigned int mul2bf(unsigned int a, unsigned int b) {
  float lo = bf2f((unsigned short)(a & 0xffffu)) * bf2f((unsigned short)(b & 0xffffu));
  float hi = bf2f((unsigned short)(a >> 16)) * bf2f((unsigned short)(b >> 16));
  return ((unsigned int)f2bf(hi) << 16) | (unsigned int)f2bf(lo);
}
__device__ __forceinline__ f32x4 mfma16(short8 a, short8 b, f32x4 c) {
  return __builtin_amdgcn_mfma_f32_16x16x32_bf16(a, b, c, 0, 0, 0);
}

constexpr int LC = 64;   // chunk length == tokens per block
constexpr int CG = 16;   // chunks per scan group

// ---------------- k0: one-time weight conversion / transpose to bf16 ----------------
__global__ __launch_bounds__(256) void k0_prep(
    const float* __restrict__ W_in, const float* __restrict__ W_x,
    const float* __restrict__ W_out,
    unsigned short* __restrict__ WinT, unsigned short* __restrict__ WxT,
    unsigned short* __restrict__ WoT)
{
  int flat = blockIdx.x * 256 + threadIdx.x;
  if (flat < 16384) {
    int n = flat >> 6, k = flat & 63;
    WinT[flat] = f2bf(W_in[k * 256 + n]);
  } else if (flat < 20480) {
    int f = flat - 16384; int n = f >> 7, k = f & 127;
    WxT[f] = (n < 20) ? f2bf(W_x[k * 20 + n]) : (unsigned short)0;
  } else if (flat < 28672) {
    int f = flat - 20480; int n = f >> 7, k = f & 127;
    WoT[f] = f2bf(W_out[k * 64 + n]);
  }
}

// ---------------- k1: hidden + MFMA in-proj + silu + MFMA x-proj + dt + chunk aggregate ----------------
__global__ __launch_bounds__(256) void k1_front(
    const float* __restrict__ x, const float* __restrict__ xres,
    const unsigned short* __restrict__ gWinT, const unsigned short* __restrict__ gWxT,
    const float* __restrict__ W_dt, const float* __restrict__ b_dt,
    const float* __restrict__ A_log,
    float* __restrict__ hidden_out,
    unsigned short* __restrict__ dt_o, unsigned short* __restrict__ xi_o,
    unsigned short* __restrict__ zs_o,
    float* __restrict__ Bm_o, float* __restrict__ Cm_o,
    float* __restrict__ aggA, float* __restrict__ aggB)
{
  __shared__ __align__(16) char smem[63488];
  unsigned short* sWinT = (unsigned short*)smem;            // 32KB [256][64] swz
  unsigned short* sXZ   = (unsigned short*)smem;            // alias after MFMA1: [64][256] swz
  unsigned short* sA    = (unsigned short*)(smem + 32768);  // 8KB [64][64] swz
  unsigned short* sWxT  = (unsigned short*)(smem + 32768);  // alias: [32][128] swz
  unsigned short* sDt   = (unsigned short*)(smem + 40960);  // 16KB [64][128]
  float* sDtr = (float*)(smem + 57344);                     // [64][5]
  float* sBm  = (float*)(smem + 58624);                     // [64][9]
  float* sWdt = (float*)(smem + 60928);                     // [4][128]
  float* sBdt = (float*)(smem + 62976);                     // [128]

  const int tid  = threadIdx.x;
  const int lane = tid & 63;
  const int w    = tid >> 6;
  const int t0   = blockIdx.x * LC;
  const int ck   = blockIdx.x;

#pragma unroll
  for (int i = 0; i < 8; ++i) {
    int f = tid + i * 256;             // uint4 index over 256x64 bf16
    int n = f >> 3, k0 = (f & 7) * 8;
    uint4 v = ((const uint4*)gWinT)[f];
    *(uint4*)&sWinT[n * 64 + (k0 ^ ((n & 7) << 3))] = v;
  }
  for (int i = tid; i < 512; i += 256) sWdt[i] = W_dt[i];
  if (tid < 128) sBdt[tid] = b_dt[tid];
#pragma unroll
  for (int i = 0; i < 4; ++i) {
    int f = tid + i * 256;             // float4 index over 64x64 f32
    int t = f >> 4, c0 = (f & 15) * 4;
    float4 xv = ((const float4*)(x    + (size_t)t0 * 64))[f];
    float4 rv = ((const float4*)(xres + (size_t)t0 * 64))[f];
    float4 h; h.x = xv.x + rv.x; h.y = xv.y + rv.y; h.z = xv.z + rv.z; h.w = xv.w + rv.w;
    ((float4*)(hidden_out + (size_t)t0 * 64))[f] = h;
    ushort4 p; p.x = f2bf(h.x); p.y = f2bf(h.y); p.z = f2bf(h.z); p.w = f2bf(h.w);
    *(ushort4*)&sA[t * 64 + (c0 ^ ((t & 7) << 3))] = p;
  }
  __syncthreads();

  // ---- MFMA1: xz[64 tok][256 n]
  f32x4 acc[4][4];
#pragma unroll
  for (int m = 0; m < 4; ++m)
#pragma unroll
    for (int n = 0; n < 4; ++n) acc[m][n] = (f32x4){0.f, 0.f, 0.f, 0.f};
#pragma unroll
  for (int ks = 0; ks < 2; ++ks) {
    int k0 = ks * 32 + ((lane >> 4) << 3);
    short8 af[4], bfr[4];
#pragma unroll
    for (int m = 0; m < 4; ++m) {
      int row = m * 16 + (lane & 15);
      af[m] = *(const short8*)&sA[row * 64 + (k0 ^ ((row & 7) << 3))];
    }
#pragma unroll
    for (int n = 0; n < 4; ++n) {
      int col = w * 64 + n * 16 + (lane & 15);
      bfr[n] = *(const short8*)&sWinT[col * 64 + (k0 ^ ((col & 7) << 3))];
    }
#pragma unroll
    for (int m = 0; m < 4; ++m)
#pragma unroll
      for (int n = 0; n < 4; ++n) acc[m][n] = mfma16(af[m], bfr[n], acc[m][n]);
  }
  __syncthreads();   // sWinT/sA dead

#pragma unroll
  for (int i = 0; i < 2; ++i) {
    int f = tid + i * 256;             // uint4 over 32x128 bf16
    int n = f >> 4, k0 = (f & 15) * 8;
    uint4 v = ((const uint4*)gWxT)[f];
    *(uint4*)&sWxT[n * 128 + (k0 ^ ((n & 7) << 3))] = v;
  }
#pragma unroll
  for (int m = 0; m < 4; ++m)
#pragma unroll
    for (int n = 0; n < 4; ++n) {
      int col = w * 64 + n * 16 + (lane & 15);
#pragma unroll
      for (int r = 0; r < 4; ++r) {
        int tok = m * 16 + ((lane >> 4) << 2) + r;
        sXZ[tok * 256 + (col ^ ((tok & 7) << 3))] = f2bf(silu_(acc[m][n][r]));
      }
    }
  __syncthreads();

#pragma unroll
  for (int i = 0; i < 8; ++i) {
    int f = tid + i * 256;             // uint4 over 64x256 bf16
    int t = f >> 5, k0 = (f & 31) * 8;
    uint4 v = *(const uint4*)&sXZ[t * 256 + (k0 ^ ((t & 7) << 3))];
    if (k0 < 128) *(uint4*)(xi_o + (size_t)(t0 + t) * 128 + k0) = v;
    else          *(uint4*)(zs_o + (size_t)(t0 + t) * 128 + (k0 - 128)) = v;
  }

  // ---- MFMA2: xdb[64 tok][20] = xi @ W_x
  f32x4 acc2[2];
  acc2[0] = (f32x4){0.f, 0.f, 0.f, 0.f};
  acc2[1] = (f32x4){0.f, 0.f, 0.f, 0.f};
#pragma unroll
  for (int ks = 0; ks < 4; ++ks) {
    int k0 = ks * 32 + ((lane >> 4) << 3);
    int arow = w * 16 + (lane & 15);
    short8 a2 = *(const short8*)&sXZ[arow * 256 + (k0 ^ ((arow & 7) << 3))];
#pragma unroll
    for (int nf = 0; nf < 2; ++nf) {
      int col = nf * 16 + (lane & 15);
      short8 b2 = *(const short8*)&sWxT[col * 128 + (k0 ^ ((col & 7) << 3))];
      acc2[nf] = mfma16(a2, b2, acc2[nf]);
    }
  }
#pragma unroll
  for (int nf = 0; nf < 2; ++nf) {
    int col = nf * 16 + (lane & 15);
#pragma unroll
    for (int r = 0; r < 4; ++r) {
      int tok = w * 16 + ((lane >> 4) << 2) + r;
      float v = acc2[nf][r];
      if (col < 4) {
        sDtr[tok * 5 + col] = v;
      } else if (col < 12) {
        sBm[tok * 9 + (col - 4)] = v;
        Bm_o[(size_t)(t0 + tok) * 8 + (col - 4)] = v;
      } else if (col < 20) {
        Cm_o[(size_t)(t0 + tok) * 8 + (col - 12)] = v;
      }
    }
  }
  __syncthreads();

  // ---- dt = softplus(dt_r @ W_dt + b_dt)
#pragma unroll
  for (int i = 0; i < 16; ++i) {
    int f = tid + i * 256;             // pair index over 64x64
    int t = f >> 6, d0 = (f & 63) * 2;
    float r0 = sDtr[t * 5 + 0], r1 = sDtr[t * 5 + 1], r2 = sDtr[t * 5 + 2], r3 = sDtr[t * 5 + 3];
    unsigned int pk = 0;
#pragma unroll
    for (int q = 0; q < 2; ++q) {
      int d = d0 + q;
      float v = sBdt[d] + r0 * sWdt[d] + r1 * sWdt[128 + d] + r2 * sWdt[256 + d] + r3 * sWdt[384 + d];
      float sp = (v > 15.f) ? v : RLOG2E * __log2f(1.f + exp2f(v * LOG2E));
      pk |= ((unsigned int)f2bf(sp)) << (16 * q);
    }
    ((unsigned int*)sDt)[t * 64 + (d0 >> 1)] = pk;
    ((unsigned int*)dt_o)[(size_t)(t0 + t) * 64 + (d0 >> 1)] = pk;
  }
  __syncthreads();

  // ---- fused chunk aggregate
  {
    const int d = tid >> 1, sh = tid & 1, s0 = sh * 4;
    float4 al = *(const float4*)(A_log + d * 8 + s0);
    float A2[4];
    A2[0] = -__expf(al.x) * LOG2E; A2[1] = -__expf(al.y) * LOG2E;
    A2[2] = -__expf(al.z) * LOG2E; A2[3] = -__expf(al.w) * LOG2E;
    float P[4] = {1.f, 1.f, 1.f, 1.f}, Bg[4] = {0.f, 0.f, 0.f, 0.f};
#pragma unroll 4
    for (int t = 0; t < LC; ++t) {
      float dtv = bf2f(sDt[t * 128 + d]);
      float xiv = bf2f(sXZ[t * 256 + (d ^ ((t & 7) << 3))]);
      float dx  = dtv * xiv;
      float b0 = sBm[t * 9 + s0], b1 = sBm[t * 9 + s0 + 1], b2 = sBm[t * 9 + s0 + 2], b3 = sBm[t * 9 + s0 + 3];
      float a;
      a = exp2f(dtv * A2[0]); P[0] *= a; Bg[0] = fmaf(Bg[0], a, dx * b0);
      a = exp2f(dtv * A2[1]); P[1] *= a; Bg[1] = fmaf(Bg[1], a, dx * b1);
      a = exp2f(dtv * A2[2]); P[2] *= a; Bg[2] = fmaf(Bg[2], a, dx * b2);
      a = exp2f(dtv * A2[3]); P[3] *= a; Bg[3] = fmaf(Bg[3], a, dx * b3);
    }
    float4 pv; pv.x = P[0];  pv.y = P[1];  pv.z = P[2];  pv.w = P[3];
    float4 bv; bv.x = Bg[0]; bv.y = Bg[1]; bv.z = Bg[2]; bv.w = Bg[3];
    *(float4*)(aggA + (size_t)ck * 1024 + tid * 4) = pv;
    *(float4*)(aggB + (size_t)ck * 1024 + tid * 4) = bv;
  }
}

// ---------------- k25a: within-group prefix scan (in-place) + group aggregate ----------------
__global__ __launch_bounds__(256) void k25a(
    float* __restrict__ aggA, float* __restrict__ aggB,
    float* __restrict__ gA, float* __restrict__ gB)
{
  const int g  = blockIdx.x >> 2;
  const int ds = ((blockIdx.x & 3) << 8) + threadIdx.x;
  float P = 1.f, B = 0.f;
  const int base = g * CG;
#pragma unroll
  for (int c = 0; c < CG; ++c) {
    size_t idx = (size_t)(base + c) * 1024 + ds;
    float a = aggA[idx], b = aggB[idx];
    aggA[idx] = P; aggB[idx] = B;
    P *= a; B = fmaf(B, a, b);
  }
  gA[(size_t)g * 1024 + ds] = P;
  gB[(size_t)g * 1024 + ds] = B;
}

// ---------------- k25b: serial scan over group aggregates ----------------
__global__ __launch_bounds__(64) void k25b(
    const float* __restrict__ gA, const float* __restrict__ gB,
    float* __restrict__ gH, int NG)
{
  int ds = blockIdx.x * 64 + threadIdx.x;
  float H = 0.f;
#pragma unroll 8
  for (int g = 0; g < NG; ++g) {
    size_t idx = (size_t)g * 1024 + ds;
    gH[idx] = H;
    H = fmaf(gA[idx], H, gB[idx]);
  }
}

// ---------------- k3: fused apply-scan + y*silu(z) + W_out MFMA + hidden add ----------------
__global__ __launch_bounds__(256) void k3_fused(
    const unsigned short* __restrict__ dt_g, const unsigned short* __restrict__ xi_g,
    const float* __restrict__ Bm_g, const float* __restrict__ Cm_g,
    const float* __restrict__ A_log, const float* __restrict__ Dvec,
    const float* __restrict__ prefA, const float* __restrict__ prefB,
    const float* __restrict__ gH,
    const unsigned short* __restrict__ zs_g, const unsigned short* __restrict__ gWoT,
    const float* __restrict__ hidden_g, float* __restrict__ out)
{
  __shared__ __align__(16) char smem[53760];
  unsigned short* sDtY = (unsigned short*)smem;            // [64][128] dt, then y in-place
  unsigned short* sXiP = (unsigned short*)(smem + 16384);  // [64][128] xi, then p=y*zs (swz)
  unsigned short* sWoT = (unsigned short*)(smem + 32768);  // [64][128] swz
  float* sBm = (float*)(smem + 49152);                     // [64][9]
  float* sCm = (float*)(smem + 51456);                     // [64][9]

  const int tid  = threadIdx.x;
  const int lane = tid & 63;
  const int w    = tid >> 6;
  const int ck   = blockIdx.x;
  const int gt0  = ck * LC;
  const int grp  = ck / CG;

  // stage dt, xi (linear), W_out (swizzled), Bm/Cm (padded)
#pragma unroll
  for (int i = 0; i < 4; ++i) {
    int f = tid + i * 256;   // uint4 over 64x128 bf16
    ((uint4*)sDtY)[f] = ((const uint4*)(dt_g + (size_t)gt0 * 128))[f];
    ((uint4*)sXiP)[f] = ((const uint4*)(xi_g + (size_t)gt0 * 128))[f];
    int n = f >> 4, k0 = (f & 15) * 8;
    uint4 v = ((const uint4*)gWoT)[f];
    *(uint4*)&sWoT[n * 128 + (k0 ^ ((n & 7) << 3))] = v;
  }
#pragma unroll
  for (int i = 0; i < 2; ++i) {
    int f = tid + i * 256;   // over 64x8 f32
    int r = f >> 3, c = f & 7;
    sBm[r * 9 + c] = Bm_g[(size_t)gt0 * 8 + f];
    sCm[r * 9 + c] = Cm_g[(size_t)gt0 * 8 + f];
  }

  const int d = tid >> 1, sh = tid & 1, s0 = sh * 4;
  float4 al = *(const float4*)(A_log + d * 8 + s0);
  float A2[4];
  A2[0] = -__expf(al.x) * LOG2E; A2[1] = -__expf(al.y) * LOG2E;
  A2[2] = -__expf(al.z) * LOG2E; A2[3] = -__expf(al.w) * LOG2E;
  float4 Alc = *(const float4*)(prefA + (size_t)ck * 1024 + tid * 4);
  float4 Blc = *(const float4*)(prefB + (size_t)ck * 1024 + tid * 4);
  float4 Hg  = *(const float4*)(gH + (size_t)grp * 1024 + tid * 4);
  float h[4];
  h[0] = fmaf(Alc.x, Hg.x, Blc.x); h[1] = fmaf(Alc.y, Hg.y, Blc.y);
  h[2] = fmaf(Alc.z, Hg.z, Blc.z); h[3] = fmaf(Alc.w, Hg.w, Blc.w);
  float Dd = Dvec[d];
  __syncthreads();

  // scan chunk; write y in-place over dt slot (safe: pair reads before write, lockstep)
#pragma unroll 4
  for (int t = 0; t < LC; ++t) {
    float dtv = bf2f(sDtY[t * 128 + d]);
    float xiv = bf2f(sXiP[t * 128 + d]);
    float dx  = dtv * xiv;
    float b0 = sBm[t * 9 + s0], b1 = sBm[t * 9 + s0 + 1], b2 = sBm[t * 9 + s0 + 2], b3 = sBm[t * 9 + s0 + 3];
    float c0 = sCm[t * 9 + s0], c1 = sCm[t * 9 + s0 + 1], c2 = sCm[t * 9 + s0 + 2], c3 = sCm[t * 9 + s0 + 3];
    float a, yp;
    a = exp2f(dtv * A2[0]); h[0] = fmaf(h[0], a, dx * b0); yp  = h[0] * c0;
    a = exp2f(dtv * A2[1]); h[1] = fmaf(h[1], a, dx * b1); yp += h[1] * c1;
    a = exp2f(dtv * A2[2]); h[2] = fmaf(h[2], a, dx * b2); yp += h[2] * c2;
    a = exp2f(dtv * A2[3]); h[3] = fmaf(h[3], a, dx * b3); yp += h[3] * c3;
    yp += __shfl_xor(yp, 1);
    if (sh == 0) sDtY[t * 128 + d] = f2bf(yp + Dd * xiv);
  }
  __syncthreads();

  // p = y * silu(z) -> sXiP (swizzled), overwriting dead xi
#pragma unroll
  for (int i = 0; i < 4; ++i) {
    int f = tid + i * 256;   // uint4 over 64x128 bf16
    int t = f >> 4, k0 = (f & 15) * 8;
    uint4 yv = ((const uint4*)sDtY)[f];
    uint4 zv = ((const uint4*)(zs_g + (size_t)gt0 * 128))[f];
    uint4 p; p.x = mul2bf(yv.x, zv.x); p.y = mul2bf(yv.y, zv.y);
    p.z = mul2bf(yv.z, zv.z); p.w = mul2bf(yv.w, zv.w);
    *(uint4*)&sXiP[t * 128 + (k0 ^ ((t & 7) << 3))] = p;
  }
  __syncthreads();

  // MFMA: out_tile[64 tok][64 c] = p @ WoT^T ; wave w owns token frag w*16..
  f32x4 acc[4];
#pragma unroll
  for (int n = 0; n < 4; ++n) acc[n] = (f32x4){0.f, 0.f, 0.f, 0.f};
#pragma unroll
  for (int ks = 0; ks < 4; ++ks) {
    int k0 = ks * 32 + ((lane >> 4) << 3);
    int arow = w * 16 + (lane & 15);
    short8 a = *(const short8*)&sXiP[arow * 128 + (k0 ^ ((arow & 7) << 3))];
#pragma unroll
    for (int nf = 0; nf < 4; ++nf) {
      int col = nf * 16 + (lane & 15);
      short8 b = *(const short8*)&sWoT[col * 128 + (k0 ^ ((col & 7) << 3))];
      acc[nf] = mfma16(a, b, acc[nf]);
    }
  }
#pragma unroll
  for (int nf = 0; nf < 4; ++nf) {
    int col = nf * 16 + (lane & 15);
#pragma unroll
    for (int r = 0; r < 4; ++r) {
      int tok = w * 16 + ((lane >> 4) << 2) + r;
      size_t idx = (size_t)(gt0 + tok) * 64 + col;
      out[idx] = acc[nf][r] + hidden_g[idx];
    }
  }
}

extern "C" void kernel_launch(void* const* d_in, const int* in_sizes, int n_in,
                              void* d_out, int out_size, void* d_ws, size_t ws_size,
                              hipStream_t stream) {
  const float* x     = (const float*)d_in[0];
  const float* xres  = (const float*)d_in[1];
  const float* W_in  = (const float*)d_in[3];
  const float* W_x   = (const float*)d_in[4];
  const float* W_dt  = (const float*)d_in[5];
  const float* b_dt  = (const float*)d_in[6];
  const float* A_log = (const float*)d_in[7];
  const float* Dv    = (const float*)d_in[8];
  const float* W_out = (const float*)d_in[9];

  const int T  = in_sizes[0] / 64;   // 65536
  const int NB = T / LC;             // 1024 chunks
  const int NC = NB;
  const int NG = NC / CG;            // 64 groups

  float* out_x = (float*)d_out;
  float* out_h = (float*)d_out + (size_t)T * 64;

  char* ws = (char*)d_ws;
  unsigned short* dt_b = (unsigned short*)ws; ws += (size_t)T * 128 * 2;
  unsigned short* xi_b = (unsigned short*)ws; ws += (size_t)T * 128 * 2;
  unsigned short* zs_b = (unsigned short*)ws; ws += (size_t)T * 128 * 2;
  float* Bm_b = (float*)ws; ws += (size_t)T * 8 * 4;
  float* Cm_b = (float*)ws; ws += (size_t)T * 8 * 4;
  float* aggA = (float*)ws; ws += (size_t)NC * 1024 * 4;   // becomes local prefix A in-place
  float* aggB = (float*)ws; ws += (size_t)NC * 1024 * 4;   // becomes local prefix B in-place
  float* gA   = (float*)ws; ws += (size_t)NG * 1024 * 4;
  float* gB   = (float*)ws; ws += (size_t)NG * 1024 * 4;
  float* gH   = (float*)ws; ws += (size_t)NG * 1024 * 4;
  unsigned short* WinT = (unsigned short*)ws; ws += 16384 * 2;
  unsigned short* WxT  = (unsigned short*)ws; ws += 4096 * 2;
  unsigned short* WoT  = (unsigned short*)ws; ws += 8192 * 2;

  k0_prep<<<112, 256, 0, stream>>>(W_in, W_x, W_out, WinT, WxT, WoT);
  k1_front<<<NB, 256, 0, stream>>>(x, xres, WinT, WxT, W_dt, b_dt, A_log,
                                   out_h, dt_b, xi_b, zs_b, Bm_b, Cm_b, aggA, aggB);
  k25a<<<NG * 4, 256, 0, stream>>>(aggA, aggB, gA, gB);
  k25b<<<16, 64, 0, stream>>>(gA, gB, gH, NG);
  k3_fused<<<NB, 256, 0, stream>>>(dt_b, xi_b, Bm_b, Cm_b, A_log, Dv,
                                   aggA, aggB, gH, zs_b, WoT, out_h, out_x);
}